// Round 2
// baseline (342.197 us; speedup 1.0000x reference)
//
#include <hip/hip_runtime.h>
#include <hip/hip_bf16.h>
#include <type_traits>

typedef unsigned short u16;
typedef __attribute__((ext_vector_type(4))) float f32x4;
typedef __attribute__((ext_vector_type(8))) short short8;
typedef __attribute__((ext_vector_type(8))) __bf16 bf16x8;

#define BB 2
#define NN 2048
#define DDIM 1024
#define HH 8
#define QHH 16
#define DHH 64

__device__ __forceinline__ float b2f(u16 v) {
    return __builtin_bit_cast(float, ((unsigned)v) << 16);
}
__device__ __forceinline__ u16 f2b(float f) {
    unsigned u = __builtin_bit_cast(unsigned, f);
    u += 0x7FFFu + ((u >> 16) & 1u);   // RNE
    return (u16)(u >> 16);
}
__device__ __forceinline__ f32x4 mfma16(short8 a, short8 b, f32x4 c) {
    return __builtin_amdgcn_mfma_f32_16x16x32_bf16(
        __builtin_bit_cast(bf16x8, a), __builtin_bit_cast(bf16x8, b), c, 0, 0, 0);
}

// ---------------- RMSNorm over tokens: [4096,1024] f32 -> bf16 ----------------
__global__ __launch_bounds__(256) void k_rmsnorm(const float* __restrict__ tokens,
                                                 const float* __restrict__ norm_w,
                                                 u16* __restrict__ xb) {
    const int row = blockIdx.x;
    const int tid = threadIdx.x;
    const float* xp = tokens + (size_t)row * DDIM + tid * 4;
    float4 raw = *(const float4*)xp;
    float ss = raw.x * raw.x + raw.y * raw.y + raw.z * raw.z + raw.w * raw.w;
#pragma unroll
    for (int d = 1; d < 64; d <<= 1) ss += __shfl_xor(ss, d);
    __shared__ float red[4];
    if ((tid & 63) == 0) red[tid >> 6] = ss;
    __syncthreads();
    float tot = red[0] + red[1] + red[2] + red[3];
    float r = rsqrtf(tot * (1.0f / 1024.0f) + 1.1920929e-7f);
    float4 wv = *(const float4*)(norm_w + tid * 4);
    ushort4 o;
    o.x = f2b(raw.x * r * wv.x);
    o.y = f2b(raw.y * r * wv.y);
    o.z = f2b(raw.z * r * wv.z);
    o.w = f2b(raw.w * r * wv.w);
    *(ushort4*)(xb + (size_t)row * DDIM + tid * 4) = o;
}

// ---------------- transpose f32 [R,C] -> bf16 [C,R] ----------------
__global__ __launch_bounds__(256) void k_transpose(const float* __restrict__ in,
                                                   u16* __restrict__ out, int R, int C) {
    __shared__ u16 tile[32][33];
    const int bc = blockIdx.x * 32, br = blockIdx.y * 32;
    const int tx = threadIdx.x & 31, ty = threadIdx.x >> 5;
#pragma unroll
    for (int i = 0; i < 32; i += 8) tile[ty + i][tx] = f2b(in[(size_t)(br + ty + i) * C + bc + tx]);
    __syncthreads();
#pragma unroll
    for (int i = 0; i < 32; i += 8) out[(size_t)(bc + ty + i) * R + br + tx] = tile[tx][ty + i];
}

// ---------------- GEMM: C[M,N] = A[M,K](bf16) x Bt[N,K](bf16) ----------------
template <typename OT>
__global__ __launch_bounds__(256) void k_gemm_bt(const u16* __restrict__ A,
                                                 const u16* __restrict__ Bt,
                                                 OT* __restrict__ C,
                                                 int M, int Ncols, int K) {
    __shared__ __attribute__((aligned(16))) u16 As[128 * 32];
    __shared__ __attribute__((aligned(16))) u16 Bs[128 * 32];
    const int tid = threadIdx.x;
    const int lane = tid & 63;
    const int w = tid >> 6;
    const int m0 = blockIdx.y * 128;
    const int n0 = blockIdx.x * 128;
    const int wr = (w >> 1) * 64;
    const int wc = (w & 1) * 64;
    const int lr = lane & 15;
    const int lq = lane >> 4;

    const int c0 = tid, c1 = tid + 256;
    const int r0 = c0 >> 2, ko0 = (c0 & 3) * 8;
    const int r1 = c1 >> 2, ko1 = (c1 & 3) * 8;

    f32x4 acc[4][4];
#pragma unroll
    for (int i = 0; i < 4; i++)
#pragma unroll
        for (int j = 0; j < 4; j++) acc[i][j] = (f32x4){0.f, 0.f, 0.f, 0.f};

    for (int k0 = 0; k0 < K; k0 += 32) {
        __syncthreads();
        *(short8*)&As[r0 * 32 + ko0] = *(const short8*)&A[(size_t)(m0 + r0) * K + k0 + ko0];
        *(short8*)&As[r1 * 32 + ko1] = *(const short8*)&A[(size_t)(m0 + r1) * K + k0 + ko1];
        *(short8*)&Bs[r0 * 32 + ko0] = *(const short8*)&Bt[(size_t)(n0 + r0) * K + k0 + ko0];
        *(short8*)&Bs[r1 * 32 + ko1] = *(const short8*)&Bt[(size_t)(n0 + r1) * K + k0 + ko1];
        __syncthreads();
        short8 a[4], b[4];
#pragma unroll
        for (int mi = 0; mi < 4; ++mi) a[mi] = *(const short8*)&As[(wr + mi * 16 + lr) * 32 + lq * 8];
#pragma unroll
        for (int ni = 0; ni < 4; ++ni) b[ni] = *(const short8*)&Bs[(wc + ni * 16 + lr) * 32 + lq * 8];
#pragma unroll
        for (int mi = 0; mi < 4; ++mi)
#pragma unroll
            for (int ni = 0; ni < 4; ++ni) acc[mi][ni] = mfma16(a[mi], b[ni], acc[mi][ni]);
    }
#pragma unroll
    for (int mi = 0; mi < 4; ++mi)
#pragma unroll
        for (int ni = 0; ni < 4; ++ni)
#pragma unroll
            for (int r = 0; r < 4; ++r) {
                int row = m0 + wr + mi * 16 + lq * 4 + r;
                int col = n0 + wc + ni * 16 + lr;
                if constexpr (std::is_same_v<OT, u16>)
                    C[(size_t)row * Ncols + col] = f2b(acc[mi][ni][r]);
                else
                    C[(size_t)row * Ncols + col] = acc[mi][ni][r];
            }
}

// ---------------- per-head L2 norm + scale; emit qn [b,qh,n,dh], kn [b,h,n,dh], vt [b,h,dh,n] ----------------
__global__ __launch_bounds__(256) void k_headnorm(const u16* __restrict__ q_raw,
                                                  const u16* __restrict__ kv_raw,
                                                  const float* __restrict__ q_gamma,
                                                  const float* __restrict__ k_gamma,
                                                  u16* __restrict__ qn,
                                                  u16* __restrict__ kn,
                                                  u16* __restrict__ vt) {
    const int row = blockIdx.x;  // b*N + n
    const int b = row >> 11, n = row & 2047;
    const int lane = threadIdx.x & 63, w = threadIdx.x >> 6;
    const u16* qr = q_raw + (size_t)row * 1024;
    const u16* kvr = kv_raw + (size_t)row * 1024;
#pragma unroll
    for (int t = 0; t < 4; ++t) {
        int qh = w * 4 + t;
        float v = b2f(qr[qh * 64 + lane]);
        float ss = v * v;
#pragma unroll
        for (int d = 1; d < 64; d <<= 1) ss += __shfl_xor(ss, d);
        float nrm = fmaxf(sqrtf(ss), 1e-12f);
        float g = q_gamma[qh * 64 + lane];
        qn[((size_t)(b * QHH + qh) * NN + n) * 64 + lane] = f2b(v / nrm * (g + 1.0f) * 8.0f);
    }
#pragma unroll
    for (int t = 0; t < 2; ++t) {
        int kh = w * 2 + t;
        float v = b2f(kvr[kh * 64 + lane]);
        float ss = v * v;
#pragma unroll
        for (int d = 1; d < 64; d <<= 1) ss += __shfl_xor(ss, d);
        float nrm = fmaxf(sqrtf(ss), 1e-12f);
        float g = k_gamma[kh * 64 + lane];
        kn[((size_t)(b * HH + kh) * NN + n) * 64 + lane] = f2b(v / nrm * (g + 1.0f) * 8.0f);
        float vv = b2f(kvr[512 + kh * 64 + lane]);
        vt[((size_t)(b * HH + kh) * 64 + lane) * NN + n] = f2b(vv);
    }
}

// ---------------- flash attention, wave = 16 query rows, j-tile = 32, online softmax ----------------
__global__ __launch_bounds__(256) void k_attn(const u16* __restrict__ qn,
                                              const u16* __restrict__ kn,
                                              const u16* __restrict__ vt,
                                              u16* __restrict__ O) {
    const int bq = blockIdx.x;
    const int b = bq >> 4, qh = bq & 15;
    const int h = qh >> 1;
    const int lane = threadIdx.x & 63, w = threadIdx.x >> 6;
    const int lr = lane & 15, lq = lane >> 4;
    const int i0 = blockIdx.y * 64 + w * 16;
    const u16* Qp = qn + (size_t)(b * QHH + qh) * NN * 64;
    const u16* Kp = kn + (size_t)(b * HH + h) * NN * 64;
    const u16* Vp = vt + (size_t)(b * HH + h) * 64 * NN;
    u16* Op = O + (size_t)(b * QHH + qh) * NN * 64;
    __shared__ __attribute__((aligned(16))) u16 Plds[4][16 * 32];
    u16* pl = Plds[w];

    short8 qf0 = *(const short8*)&Qp[(size_t)(i0 + lr) * 64 + lq * 8];
    short8 qf1 = *(const short8*)&Qp[(size_t)(i0 + lr) * 64 + 32 + lq * 8];

    f32x4 of[4];
#pragma unroll
    for (int nt = 0; nt < 4; ++nt) of[nt] = (f32x4){0.f, 0.f, 0.f, 0.f};
    float mrow[4] = {-1e30f, -1e30f, -1e30f, -1e30f};
    float lrow[4] = {0.f, 0.f, 0.f, 0.f};

    const int jtmax = (i0 + 15) >> 5;
    for (int jt = 0; jt <= jtmax; ++jt) {
        const int j0 = jt * 32;
        f32x4 s[2];
#pragma unroll
        for (int ct = 0; ct < 2; ++ct) {
            short8 kf0 = *(const short8*)&Kp[(size_t)(j0 + ct * 16 + lr) * 64 + lq * 8];
            short8 kf1 = *(const short8*)&Kp[(size_t)(j0 + ct * 16 + lr) * 64 + 32 + lq * 8];
            f32x4 t = (f32x4){0.f, 0.f, 0.f, 0.f};
            t = mfma16(qf0, kf0, t);
            t = mfma16(qf1, kf1, t);
            s[ct] = t;
        }
        float sv[2][4];
#pragma unroll
        for (int ct = 0; ct < 2; ++ct)
#pragma unroll
            for (int r = 0; r < 4; ++r) {
                int rowi = i0 + lq * 4 + r;
                int col = j0 + ct * 16 + lr;
                float x = s[ct][r] * (1.0f / 50.0f);
                x = fminf(fmaxf(x, -15.0f), 15.0f);
                float e = __expf(2.0f * x);
                float val = ((e - 1.0f) / (e + 1.0f)) * (50.0f * 0.125f);  // tanh softcap * dh^-0.5
                sv[ct][r] = (col <= rowi) ? val : -1e30f;
            }
        float alpha[4];
        float ps[2][4];
#pragma unroll
        for (int r = 0; r < 4; ++r) {
            float mx = fmaxf(sv[0][r], sv[1][r]);
#pragma unroll
            for (int d = 1; d < 16; d <<= 1) mx = fmaxf(mx, __shfl_xor(mx, d));
            float mnew = fmaxf(mrow[r], mx);
            alpha[r] = __expf(mrow[r] - mnew);
            float p0 = __expf(sv[0][r] - mnew);
            float p1 = __expf(sv[1][r] - mnew);
            ps[0][r] = p0;
            ps[1][r] = p1;
            float su = p0 + p1;
#pragma unroll
            for (int d = 1; d < 16; d <<= 1) su += __shfl_xor(su, d);
            lrow[r] = lrow[r] * alpha[r] + su;
            mrow[r] = mnew;
        }
        // P: C-layout -> LDS -> A-layout (wave-local; DS is in-order per wave,
        // but pin the compiler: scalar u16 stores then short8 load must not reorder)
#pragma unroll
        for (int ct = 0; ct < 2; ++ct)
#pragma unroll
            for (int r = 0; r < 4; ++r) pl[(lq * 4 + r) * 32 + ct * 16 + lr] = f2b(ps[ct][r]);
        asm volatile("s_waitcnt lgkmcnt(0)" ::: "memory");
        short8 pf = *(const short8*)&pl[lr * 32 + lq * 8];
#pragma unroll
        for (int nt = 0; nt < 4; ++nt) {
#pragma unroll
            for (int r = 0; r < 4; ++r) of[nt][r] *= alpha[r];
            short8 vf = *(const short8*)&Vp[(size_t)(nt * 16 + lr) * NN + j0 + lq * 8];
            of[nt] = mfma16(pf, vf, of[nt]);
        }
    }
#pragma unroll
    for (int nt = 0; nt < 4; ++nt)
#pragma unroll
        for (int r = 0; r < 4; ++r) {
            int rowi = i0 + lq * 4 + r;
            Op[(size_t)rowi * 64 + nt * 16 + lr] = f2b(of[nt][r] / lrow[r]);
        }
}

// ---------------- sum g=2 group outputs: AO[b,n,h*64+d] = O[b,2h,n,d]+O[b,2h+1,n,d] ----------------
__global__ __launch_bounds__(256) void k_gsum(const u16* __restrict__ O, u16* __restrict__ AO) {
    int idx = blockIdx.x * 256 + threadIdx.x;  // B*N*512
    int c = idx & 511, row = idx >> 9;
    int b = row >> 11, n = row & 2047;
    int hh = c >> 6, d = c & 63;
    float a = b2f(O[((size_t)(b * QHH + 2 * hh) * NN + n) * 64 + d]);
    float bb = b2f(O[((size_t)(b * QHH + 2 * hh + 1) * NN + n) * 64 + d]);
    AO[(size_t)row * 512 + c] = f2b(a + bb);
}

extern "C" void kernel_launch(void* const* d_in, const int* in_sizes, int n_in,
                              void* d_out, int out_size, void* d_ws, size_t ws_size,
                              hipStream_t stream) {
    const float* tokens = (const float*)d_in[0];
    const float* norm_w = (const float*)d_in[1];
    const float* Wq = (const float*)d_in[2];
    const float* Wkv = (const float*)d_in[3];
    const float* Wout = (const float*)d_in[4];
    const float* q_gamma = (const float*)d_in[5];
    const float* k_gamma = (const float*)d_in[6];
    float* out = (float*)d_out;

    char* ws = (char*)d_ws;
    u16* xb = (u16*)(ws + 0);             // 8,388,608 B  [4096,1024]
    u16* WqT = (u16*)(ws + 8388608);      // 2,097,152 B
    u16* WkvT = (u16*)(ws + 10485760);    // 2,097,152 B
    u16* WoutT = (u16*)(ws + 12582912);   // 1,048,576 B
    u16* q_raw = (u16*)(ws + 13631488);   // 8,388,608 B
    u16* kv_raw = (u16*)(ws + 22020096);  // 8,388,608 B
    u16* kn = (u16*)(ws + 30408704);      // 4,194,304 B
    u16* vtb = (u16*)(ws + 34603008);     // 4,194,304 B
    // total 38,797,312 B; lifetime-based aliases (stream-ordered, no overlap in use):
    u16* qn = xb;       // xb dead after the two QKV GEMMs
    u16* Obuf = q_raw;  // q_raw dead after k_headnorm
    u16* AO = kv_raw;   // kv_raw dead after k_headnorm

    k_rmsnorm<<<4096, 256, 0, stream>>>(tokens, norm_w, xb);
    k_transpose<<<dim3(32, 32), 256, 0, stream>>>(Wq, WqT, 1024, 1024);
    k_transpose<<<dim3(32, 32), 256, 0, stream>>>(Wkv, WkvT, 1024, 1024);
    k_transpose<<<dim3(32, 16), 256, 0, stream>>>(Wout, WoutT, 512, 1024);
    k_gemm_bt<u16><<<dim3(8, 32), 256, 0, stream>>>(xb, WqT, q_raw, 4096, 1024, 1024);
    k_gemm_bt<u16><<<dim3(8, 32), 256, 0, stream>>>(xb, WkvT, kv_raw, 4096, 1024, 1024);
    k_headnorm<<<4096, 256, 0, stream>>>(q_raw, kv_raw, q_gamma, k_gamma, qn, kn, vtb);
    k_attn<<<dim3(32, 32), 256, 0, stream>>>(qn, kn, vtb, Obuf);
    k_gsum<<<8192, 256, 0, stream>>>(Obuf, AO);
    k_gemm_bt<float><<<dim3(8, 32), 256, 0, stream>>>(AO, WoutT, out, 4096, 1024, 512);
}

// Round 3
// 322.552 us; speedup vs baseline: 1.0609x; 1.0609x over previous
//
#include <hip/hip_runtime.h>
#include <hip/hip_bf16.h>
#include <type_traits>

typedef unsigned short u16;
typedef __attribute__((ext_vector_type(4))) float f32x4;
typedef __attribute__((ext_vector_type(8))) short short8;
typedef __attribute__((ext_vector_type(8))) __bf16 bf16x8;

#define BB 2
#define NN 2048
#define DDIM 1024
#define HH 8
#define QHH 16
#define DHH 64

__device__ __forceinline__ float b2f(u16 v) {
    return __builtin_bit_cast(float, ((unsigned)v) << 16);
}
__device__ __forceinline__ u16 f2b(float f) {
    unsigned u = __builtin_bit_cast(unsigned, f);
    u += 0x7FFFu + ((u >> 16) & 1u);   // RNE
    return (u16)(u >> 16);
}
__device__ __forceinline__ f32x4 mfma16(short8 a, short8 b, f32x4 c) {
    return __builtin_amdgcn_mfma_f32_16x16x32_bf16(
        __builtin_bit_cast(bf16x8, a), __builtin_bit_cast(bf16x8, b), c, 0, 0, 0);
}

// ---------------- RMSNorm over tokens: [4096,1024] f32 -> bf16 ----------------
__global__ __launch_bounds__(256) void k_rmsnorm(const float* __restrict__ tokens,
                                                 const float* __restrict__ norm_w,
                                                 u16* __restrict__ xb) {
    const int row = blockIdx.x;
    const int tid = threadIdx.x;
    const float* xp = tokens + (size_t)row * DDIM + tid * 4;
    float4 raw = *(const float4*)xp;
    float ss = raw.x * raw.x + raw.y * raw.y + raw.z * raw.z + raw.w * raw.w;
#pragma unroll
    for (int d = 1; d < 64; d <<= 1) ss += __shfl_xor(ss, d);
    __shared__ float red[4];
    if ((tid & 63) == 0) red[tid >> 6] = ss;
    __syncthreads();
    float tot = red[0] + red[1] + red[2] + red[3];
    float r = rsqrtf(tot * (1.0f / 1024.0f) + 1.1920929e-7f);
    float4 wv = *(const float4*)(norm_w + tid * 4);
    ushort4 o;
    o.x = f2b(raw.x * r * wv.x);
    o.y = f2b(raw.y * r * wv.y);
    o.z = f2b(raw.z * r * wv.z);
    o.w = f2b(raw.w * r * wv.w);
    *(ushort4*)(xb + (size_t)row * DDIM + tid * 4) = o;
}

// ---------------- transpose f32 [R,C] -> bf16 [C,R] ----------------
__global__ __launch_bounds__(256) void k_transpose(const float* __restrict__ in,
                                                   u16* __restrict__ out, int R, int C) {
    __shared__ u16 tile[32][33];
    const int bc = blockIdx.x * 32, br = blockIdx.y * 32;
    const int tx = threadIdx.x & 31, ty = threadIdx.x >> 5;
#pragma unroll
    for (int i = 0; i < 32; i += 8) tile[ty + i][tx] = f2b(in[(size_t)(br + ty + i) * C + bc + tx]);
    __syncthreads();
#pragma unroll
    for (int i = 0; i < 32; i += 8) out[(size_t)(bc + ty + i) * R + br + tx] = tile[tx][ty + i];
}

// ---------------- GEMM: C[M,N] = A[M,K](bf16) x Bt[N,K](bf16) ----------------
template <typename OT>
__global__ __launch_bounds__(256) void k_gemm_bt(const u16* __restrict__ A,
                                                 const u16* __restrict__ Bt,
                                                 OT* __restrict__ C,
                                                 int M, int Ncols, int K) {
    __shared__ __attribute__((aligned(16))) u16 As[128 * 32];
    __shared__ __attribute__((aligned(16))) u16 Bs[128 * 32];
    const int tid = threadIdx.x;
    const int lane = tid & 63;
    const int w = tid >> 6;
    const int m0 = blockIdx.y * 128;
    const int n0 = blockIdx.x * 128;
    const int wr = (w >> 1) * 64;
    const int wc = (w & 1) * 64;
    const int lr = lane & 15;
    const int lq = lane >> 4;

    const int c0 = tid, c1 = tid + 256;
    const int r0 = c0 >> 2, ko0 = (c0 & 3) * 8;
    const int r1 = c1 >> 2, ko1 = (c1 & 3) * 8;

    f32x4 acc[4][4];
#pragma unroll
    for (int i = 0; i < 4; i++)
#pragma unroll
        for (int j = 0; j < 4; j++) acc[i][j] = (f32x4){0.f, 0.f, 0.f, 0.f};

    for (int k0 = 0; k0 < K; k0 += 32) {
        __syncthreads();
        *(short8*)&As[r0 * 32 + ko0] = *(const short8*)&A[(size_t)(m0 + r0) * K + k0 + ko0];
        *(short8*)&As[r1 * 32 + ko1] = *(const short8*)&A[(size_t)(m0 + r1) * K + k0 + ko1];
        *(short8*)&Bs[r0 * 32 + ko0] = *(const short8*)&Bt[(size_t)(n0 + r0) * K + k0 + ko0];
        *(short8*)&Bs[r1 * 32 + ko1] = *(const short8*)&Bt[(size_t)(n0 + r1) * K + k0 + ko1];
        __syncthreads();
        short8 a[4], b[4];
#pragma unroll
        for (int mi = 0; mi < 4; ++mi) a[mi] = *(const short8*)&As[(wr + mi * 16 + lr) * 32 + lq * 8];
#pragma unroll
        for (int ni = 0; ni < 4; ++ni) b[ni] = *(const short8*)&Bs[(wc + ni * 16 + lr) * 32 + lq * 8];
#pragma unroll
        for (int mi = 0; mi < 4; ++mi)
#pragma unroll
            for (int ni = 0; ni < 4; ++ni) acc[mi][ni] = mfma16(a[mi], b[ni], acc[mi][ni]);
    }
#pragma unroll
    for (int mi = 0; mi < 4; ++mi)
#pragma unroll
        for (int ni = 0; ni < 4; ++ni)
#pragma unroll
            for (int r = 0; r < 4; ++r) {
                int row = m0 + wr + mi * 16 + lq * 4 + r;
                int col = n0 + wc + ni * 16 + lr;
                if constexpr (std::is_same_v<OT, u16>)
                    C[(size_t)row * Ncols + col] = f2b(acc[mi][ni][r]);
                else
                    C[(size_t)row * Ncols + col] = acc[mi][ni][r];
            }
}

// ---------------- per-head L2 norm + scale; emit qn [b,qh,n,dh], kn [b,h,n,dh], vt [b,h,dh,n] ----------------
__global__ __launch_bounds__(256) void k_headnorm(const u16* __restrict__ q_raw,
                                                  const u16* __restrict__ kv_raw,
                                                  const float* __restrict__ q_gamma,
                                                  const float* __restrict__ k_gamma,
                                                  u16* __restrict__ qn,
                                                  u16* __restrict__ kn,
                                                  u16* __restrict__ vt) {
    const int row = blockIdx.x;  // b*N + n
    const int b = row >> 11, n = row & 2047;
    const int lane = threadIdx.x & 63, w = threadIdx.x >> 6;
    const u16* qr = q_raw + (size_t)row * 1024;
    const u16* kvr = kv_raw + (size_t)row * 1024;
#pragma unroll
    for (int t = 0; t < 4; ++t) {
        int qh = w * 4 + t;
        float v = b2f(qr[qh * 64 + lane]);
        float ss = v * v;
#pragma unroll
        for (int d = 1; d < 64; d <<= 1) ss += __shfl_xor(ss, d);
        float nrm = fmaxf(sqrtf(ss), 1e-12f);
        float g = q_gamma[qh * 64 + lane];
        qn[((size_t)(b * QHH + qh) * NN + n) * 64 + lane] = f2b(v / nrm * (g + 1.0f) * 8.0f);
    }
#pragma unroll
    for (int t = 0; t < 2; ++t) {
        int kh = w * 2 + t;
        float v = b2f(kvr[kh * 64 + lane]);
        float ss = v * v;
#pragma unroll
        for (int d = 1; d < 64; d <<= 1) ss += __shfl_xor(ss, d);
        float nrm = fmaxf(sqrtf(ss), 1e-12f);
        float g = k_gamma[kh * 64 + lane];
        kn[((size_t)(b * HH + kh) * NN + n) * 64 + lane] = f2b(v / nrm * (g + 1.0f) * 8.0f);
        float vv = b2f(kvr[512 + kh * 64 + lane]);
        vt[((size_t)(b * HH + kh) * 64 + lane) * NN + n] = f2b(vv);
    }
}

// ---------------- flash attention v2: fixed-max softmax (softcap bounds scores at ±6.25),
// wave = 16 q-rows, j-tile = 64, no in-loop shuffles, balanced strip remap ----------------
__global__ __launch_bounds__(256) void k_attn(const u16* __restrict__ qn,
                                              const u16* __restrict__ kn,
                                              const u16* __restrict__ vt,
                                              u16* __restrict__ O) {
    const int bq = blockIdx.x;
    const int b = bq >> 4, qh = bq & 15;
    const int h = qh >> 1;
    const int lane = threadIdx.x & 63, w = threadIdx.x >> 6;
    const int lr = lane & 15, lq = lane >> 4;
    // balance remap: CU hosting blocks {y0, y0+8, y0+16, y0+24} gets strips {a,15-a,16+a,31-a}
    // whose causal work sums to a constant (assumes ~round-robin dispatch; perf-only heuristic)
    const int yy = blockIdx.y;
    const int ya = yy & 7, yb = yy >> 3;
    const int z = ((yb & 2) << 3) | ((yb & 1) ? (15 - ya) : ya);
    const int i0 = z * 64 + w * 16;

    const u16* Qp = qn + (size_t)(b * QHH + qh) * NN * 64;
    const u16* Kp = kn + (size_t)(b * HH + h) * NN * 64;
    const u16* Vp = vt + (size_t)(b * HH + h) * 64 * NN;
    u16* Op = O + (size_t)(b * QHH + qh) * NN * 64;

    constexpr int PST = 68;  // P row stride: 64+4 spreads ds_write_b16 across all 32 banks
    __shared__ __attribute__((aligned(16))) u16 Plds[4][16 * PST];
    u16* pl = Plds[w];

    short8 qf0 = *(const short8*)&Qp[(size_t)(i0 + lr) * 64 + lq * 8];
    short8 qf1 = *(const short8*)&Qp[(size_t)(i0 + lr) * 64 + 32 + lq * 8];

    f32x4 of[4];
#pragma unroll
    for (int nt = 0; nt < 4; ++nt) of[nt] = (f32x4){0.f, 0.f, 0.f, 0.f};
    float lsum[4] = {0.f, 0.f, 0.f, 0.f};

    const int rowi_base = i0 + lq * 4;

    auto do_tile = [&](int j0, bool masked) {
        f32x4 s[4];
#pragma unroll
        for (int ct = 0; ct < 4; ++ct) {
            short8 kf0 = *(const short8*)&Kp[(size_t)(j0 + ct * 16 + lr) * 64 + lq * 8];
            short8 kf1 = *(const short8*)&Kp[(size_t)(j0 + ct * 16 + lr) * 64 + 32 + lq * 8];
            f32x4 t = (f32x4){0.f, 0.f, 0.f, 0.f};
            t = mfma16(qf0, kf0, t);
            t = mfma16(qf1, kf1, t);
            s[ct] = t;
        }
        // p = exp(6.25*tanh(s/50) - 6.25) = exp(-12.5/(exp(s*0.04)+1)); softmax max fixed at 6.25
#pragma unroll
        for (int ct = 0; ct < 4; ++ct)
#pragma unroll
            for (int r = 0; r < 4; ++r) {
                float e = __expf(s[ct][r] * 0.04f);
                float p = __expf(-12.5f / (e + 1.0f));
                if (masked) {
                    int col = j0 + ct * 16 + lr;
                    p = (col <= rowi_base + r) ? p : 0.0f;
                }
                lsum[r] += p;
                pl[(lq * 4 + r) * PST + ct * 16 + lr] = f2b(p);
            }
        // C-layout -> LDS -> A-layout; wave-local, DS unit in-order per wave; pin compiler
        asm volatile("s_waitcnt lgkmcnt(0)" ::: "memory");
        short8 pf0 = *(const short8*)&pl[lr * PST + lq * 8];
        short8 pf1 = *(const short8*)&pl[lr * PST + 32 + lq * 8];
#pragma unroll
        for (int nt = 0; nt < 4; ++nt) {
            short8 vf0 = *(const short8*)&Vp[(size_t)(nt * 16 + lr) * NN + j0 + lq * 8];
            short8 vf1 = *(const short8*)&Vp[(size_t)(nt * 16 + lr) * NN + j0 + 32 + lq * 8];
            of[nt] = mfma16(pf0, vf0, of[nt]);
            of[nt] = mfma16(pf1, vf1, of[nt]);
        }
    };

    const int jtmax = (i0 + 15) >> 6;
    for (int jt = 0; jt < jtmax; ++jt) do_tile(jt * 64, false);
    do_tile(jtmax * 64, true);

    // one row-sum reduction at the end (lanes sharing a row differ only in lr bits 0..3)
#pragma unroll
    for (int r = 0; r < 4; ++r) {
        float s2 = lsum[r];
#pragma unroll
        for (int d = 1; d < 16; d <<= 1) s2 += __shfl_xor(s2, d);
        lsum[r] = s2;
    }
#pragma unroll
    for (int nt = 0; nt < 4; ++nt)
#pragma unroll
        for (int r = 0; r < 4; ++r)
            Op[(size_t)(rowi_base + r) * 64 + nt * 16 + lr] = f2b(of[nt][r] / lsum[r]);
}

// ---------------- sum g=2 group outputs: AO[b,n,h*64+d] = O[b,2h,n,d]+O[b,2h+1,n,d] ----------------
__global__ __launch_bounds__(256) void k_gsum(const u16* __restrict__ O, u16* __restrict__ AO) {
    int idx = blockIdx.x * 256 + threadIdx.x;  // B*N*512
    int c = idx & 511, row = idx >> 9;
    int b = row >> 11, n = row & 2047;
    int hh = c >> 6, d = c & 63;
    float a = b2f(O[((size_t)(b * QHH + 2 * hh) * NN + n) * 64 + d]);
    float bb = b2f(O[((size_t)(b * QHH + 2 * hh + 1) * NN + n) * 64 + d]);
    AO[(size_t)row * 512 + c] = f2b(a + bb);
}

extern "C" void kernel_launch(void* const* d_in, const int* in_sizes, int n_in,
                              void* d_out, int out_size, void* d_ws, size_t ws_size,
                              hipStream_t stream) {
    const float* tokens = (const float*)d_in[0];
    const float* norm_w = (const float*)d_in[1];
    const float* Wq = (const float*)d_in[2];
    const float* Wkv = (const float*)d_in[3];
    const float* Wout = (const float*)d_in[4];
    const float* q_gamma = (const float*)d_in[5];
    const float* k_gamma = (const float*)d_in[6];
    float* out = (float*)d_out;

    char* ws = (char*)d_ws;
    u16* xb = (u16*)(ws + 0);             // 8,388,608 B  [4096,1024]
    u16* WqT = (u16*)(ws + 8388608);      // 2,097,152 B
    u16* WkvT = (u16*)(ws + 10485760);    // 2,097,152 B
    u16* WoutT = (u16*)(ws + 12582912);   // 1,048,576 B
    u16* q_raw = (u16*)(ws + 13631488);   // 8,388,608 B
    u16* kv_raw = (u16*)(ws + 22020096);  // 8,388,608 B
    u16* kn = (u16*)(ws + 30408704);      // 4,194,304 B
    u16* vtb = (u16*)(ws + 34603008);     // 4,194,304 B
    // total 38,797,312 B; lifetime-based aliases (stream-ordered, no overlap in use):
    u16* qn = xb;       // xb dead after the two QKV GEMMs
    u16* Obuf = q_raw;  // q_raw dead after k_headnorm
    u16* AO = kv_raw;   // kv_raw dead after k_headnorm

    k_rmsnorm<<<4096, 256, 0, stream>>>(tokens, norm_w, xb);
    k_transpose<<<dim3(32, 32), 256, 0, stream>>>(Wq, WqT, 1024, 1024);
    k_transpose<<<dim3(32, 32), 256, 0, stream>>>(Wkv, WkvT, 1024, 1024);
    k_transpose<<<dim3(32, 16), 256, 0, stream>>>(Wout, WoutT, 512, 1024);
    k_gemm_bt<u16><<<dim3(8, 32), 256, 0, stream>>>(xb, WqT, q_raw, 4096, 1024, 1024);
    k_gemm_bt<u16><<<dim3(8, 32), 256, 0, stream>>>(xb, WkvT, kv_raw, 4096, 1024, 1024);
    k_headnorm<<<4096, 256, 0, stream>>>(q_raw, kv_raw, q_gamma, k_gamma, qn, kn, vtb);
    k_attn<<<dim3(32, 32), 256, 0, stream>>>(qn, kn, vtb, Obuf);
    k_gsum<<<8192, 256, 0, stream>>>(Obuf, AO);
    k_gemm_bt<float><<<dim3(8, 32), 256, 0, stream>>>(AO, WoutT, out, 4096, 1024, 512);
}

// Round 5
// 301.985 us; speedup vs baseline: 1.1332x; 1.0681x over previous
//
#include <hip/hip_runtime.h>
#include <hip/hip_bf16.h>
#include <type_traits>

typedef unsigned short u16;
typedef __attribute__((ext_vector_type(4))) float f32x4;
typedef __attribute__((ext_vector_type(8))) short short8;
typedef __attribute__((ext_vector_type(8))) __bf16 bf16x8;

#define BB 2
#define NN 2048
#define DDIM 1024
#define HH 8
#define QHH 16
#define DHH 64

__device__ __forceinline__ float b2f(u16 v) {
    return __builtin_bit_cast(float, ((unsigned)v) << 16);
}
__device__ __forceinline__ u16 f2b(float f) {
    unsigned u = __builtin_bit_cast(unsigned, f);
    u += 0x7FFFu + ((u >> 16) & 1u);   // RNE
    return (u16)(u >> 16);
}
__device__ __forceinline__ float fastrcp(float x) {
#if __has_builtin(__builtin_amdgcn_rcpf)
    return __builtin_amdgcn_rcpf(x);   // v_rcp_f32, ~1 ulp — plenty for bf16 output
#else
    return 1.0f / x;
#endif
}
__device__ __forceinline__ float fastexp2(float x) {
#if __has_builtin(__builtin_amdgcn_exp2f)
    return __builtin_amdgcn_exp2f(x);  // v_exp_f32 (base-2); NB: __exp2f collides with glibc
#else
    return exp2f(x);
#endif
}
__device__ __forceinline__ f32x4 mfma16(short8 a, short8 b, f32x4 c) {
    return __builtin_amdgcn_mfma_f32_16x16x32_bf16(
        __builtin_bit_cast(bf16x8, a), __builtin_bit_cast(bf16x8, b), c, 0, 0, 0);
}

// ---------------- RMSNorm over tokens: [4096,1024] f32 -> bf16 ----------------
__global__ __launch_bounds__(256) void k_rmsnorm(const float* __restrict__ tokens,
                                                 const float* __restrict__ norm_w,
                                                 u16* __restrict__ xb) {
    const int row = blockIdx.x;
    const int tid = threadIdx.x;
    const float* xp = tokens + (size_t)row * DDIM + tid * 4;
    float4 raw = *(const float4*)xp;
    float ss = raw.x * raw.x + raw.y * raw.y + raw.z * raw.z + raw.w * raw.w;
#pragma unroll
    for (int d = 1; d < 64; d <<= 1) ss += __shfl_xor(ss, d);
    __shared__ float red[4];
    if ((tid & 63) == 0) red[tid >> 6] = ss;
    __syncthreads();
    float tot = red[0] + red[1] + red[2] + red[3];
    float r = rsqrtf(tot * (1.0f / 1024.0f) + 1.1920929e-7f);
    float4 wv = *(const float4*)(norm_w + tid * 4);
    ushort4 o;
    o.x = f2b(raw.x * r * wv.x);
    o.y = f2b(raw.y * r * wv.y);
    o.z = f2b(raw.z * r * wv.z);
    o.w = f2b(raw.w * r * wv.w);
    *(ushort4*)(xb + (size_t)row * DDIM + tid * 4) = o;
}

// ---------------- transpose f32 [R,C] -> bf16 [C,R] ----------------
__global__ __launch_bounds__(256) void k_transpose(const float* __restrict__ in,
                                                   u16* __restrict__ out, int R, int C) {
    __shared__ u16 tile[32][33];
    const int bc = blockIdx.x * 32, br = blockIdx.y * 32;
    const int tx = threadIdx.x & 31, ty = threadIdx.x >> 5;
#pragma unroll
    for (int i = 0; i < 32; i += 8) tile[ty + i][tx] = f2b(in[(size_t)(br + ty + i) * C + bc + tx]);
    __syncthreads();
#pragma unroll
    for (int i = 0; i < 32; i += 8) out[(size_t)(bc + ty + i) * R + br + tx] = tile[tx][ty + i];
}

// ---------------- GEMM: C[M,N] = A[M,K](bf16) x Bt[N,K](bf16) ----------------
template <typename OT>
__global__ __launch_bounds__(256) void k_gemm_bt(const u16* __restrict__ A,
                                                 const u16* __restrict__ Bt,
                                                 OT* __restrict__ C,
                                                 int M, int Ncols, int K) {
    __shared__ __attribute__((aligned(16))) u16 As[128 * 32];
    __shared__ __attribute__((aligned(16))) u16 Bs[128 * 32];
    const int tid = threadIdx.x;
    const int lane = tid & 63;
    const int w = tid >> 6;
    const int m0 = blockIdx.y * 128;
    const int n0 = blockIdx.x * 128;
    const int wr = (w >> 1) * 64;
    const int wc = (w & 1) * 64;
    const int lr = lane & 15;
    const int lq = lane >> 4;

    const int c0 = tid, c1 = tid + 256;
    const int r0 = c0 >> 2, ko0 = (c0 & 3) * 8;
    const int r1 = c1 >> 2, ko1 = (c1 & 3) * 8;

    f32x4 acc[4][4];
#pragma unroll
    for (int i = 0; i < 4; i++)
#pragma unroll
        for (int j = 0; j < 4; j++) acc[i][j] = (f32x4){0.f, 0.f, 0.f, 0.f};

    for (int k0 = 0; k0 < K; k0 += 32) {
        __syncthreads();
        *(short8*)&As[r0 * 32 + ko0] = *(const short8*)&A[(size_t)(m0 + r0) * K + k0 + ko0];
        *(short8*)&As[r1 * 32 + ko1] = *(const short8*)&A[(size_t)(m0 + r1) * K + k0 + ko1];
        *(short8*)&Bs[r0 * 32 + ko0] = *(const short8*)&Bt[(size_t)(n0 + r0) * K + k0 + ko0];
        *(short8*)&Bs[r1 * 32 + ko1] = *(const short8*)&Bt[(size_t)(n0 + r1) * K + k0 + ko1];
        __syncthreads();
        short8 a[4], b[4];
#pragma unroll
        for (int mi = 0; mi < 4; ++mi) a[mi] = *(const short8*)&As[(wr + mi * 16 + lr) * 32 + lq * 8];
#pragma unroll
        for (int ni = 0; ni < 4; ++ni) b[ni] = *(const short8*)&Bs[(wc + ni * 16 + lr) * 32 + lq * 8];
#pragma unroll
        for (int mi = 0; mi < 4; ++mi)
#pragma unroll
            for (int ni = 0; ni < 4; ++ni) acc[mi][ni] = mfma16(a[mi], b[ni], acc[mi][ni]);
    }
#pragma unroll
    for (int mi = 0; mi < 4; ++mi)
#pragma unroll
        for (int ni = 0; ni < 4; ++ni)
#pragma unroll
            for (int r = 0; r < 4; ++r) {
                int row = m0 + wr + mi * 16 + lq * 4 + r;
                int col = n0 + wc + ni * 16 + lr;
                if constexpr (std::is_same_v<OT, u16>)
                    C[(size_t)row * Ncols + col] = f2b(acc[mi][ni][r]);
                else
                    C[(size_t)row * Ncols + col] = acc[mi][ni][r];
            }
}

// ---------------- per-head L2 norm + scale; emit qn [b,qh,n,dh], kn [b,h,n,dh], vt [b,h,dh,n] ----------------
__global__ __launch_bounds__(256) void k_headnorm(const u16* __restrict__ q_raw,
                                                  const u16* __restrict__ kv_raw,
                                                  const float* __restrict__ q_gamma,
                                                  const float* __restrict__ k_gamma,
                                                  u16* __restrict__ qn,
                                                  u16* __restrict__ kn,
                                                  u16* __restrict__ vt) {
    const int row = blockIdx.x;  // b*N + n
    const int b = row >> 11, n = row & 2047;
    const int lane = threadIdx.x & 63, w = threadIdx.x >> 6;
    const u16* qr = q_raw + (size_t)row * 1024;
    const u16* kvr = kv_raw + (size_t)row * 1024;
#pragma unroll
    for (int t = 0; t < 4; ++t) {
        int qh = w * 4 + t;
        float v = b2f(qr[qh * 64 + lane]);
        float ss = v * v;
#pragma unroll
        for (int d = 1; d < 64; d <<= 1) ss += __shfl_xor(ss, d);
        float nrm = fmaxf(sqrtf(ss), 1e-12f);
        float g = q_gamma[qh * 64 + lane];
        qn[((size_t)(b * QHH + qh) * NN + n) * 64 + lane] = f2b(v / nrm * (g + 1.0f) * 8.0f);
    }
#pragma unroll
    for (int t = 0; t < 2; ++t) {
        int kh = w * 2 + t;
        float v = b2f(kvr[kh * 64 + lane]);
        float ss = v * v;
#pragma unroll
        for (int d = 1; d < 64; d <<= 1) ss += __shfl_xor(ss, d);
        float nrm = fmaxf(sqrtf(ss), 1e-12f);
        float g = k_gamma[kh * 64 + lane];
        kn[((size_t)(b * HH + kh) * NN + n) * 64 + lane] = f2b(v / nrm * (g + 1.0f) * 8.0f);
        float vv = b2f(kvr[512 + kh * 64 + lane]);
        vt[((size_t)(b * HH + kh) * 64 + lane) * NN + n] = f2b(vv);
    }
}

// ---------------- flash attention v3: fixed-max softmax, 128-thr blocks (2 waves x 16 rows),
// VALU-lean softcap (exp2+rcp), pointer-increment addressing, V register prefetch ----------------
__global__ __launch_bounds__(128) void k_attn(const u16* __restrict__ qn,
                                              const u16* __restrict__ kn,
                                              const u16* __restrict__ vt,
                                              u16* __restrict__ O) {
    const int bq = blockIdx.x;  // b*16+qh
    const int b = bq >> 4, qh = bq & 15;
    const int h = qh >> 1;
    const int lane = threadIdx.x & 63, w = threadIdx.x >> 6;  // w in {0,1}
    const int lr = lane & 15, lq = lane >> 4;
    // balanced z-remap: same CU (round-robin => fixed a=yy&7) gets z set {8b + (b odd? 7-a : a)},
    // sum over b=0..7 is 252 = const  => equal causal work per CU (perf heuristic only)
    const int yy = blockIdx.y;  // 0..63
    const int a = yy & 7, bbq = yy >> 3;
    const int z = 8 * bbq + ((bbq & 1) ? (7 - a) : a);
    const int i0 = z * 32 + w * 16;

    const u16* Qp = qn + (size_t)(b * QHH + qh) * NN * 64;
    const u16* Kp = kn + (size_t)(b * HH + h) * NN * 64;
    const u16* Vp = vt + (size_t)(b * HH + h) * 64 * NN;
    u16* Op = O + (size_t)(b * QHH + qh) * NN * 64;

    constexpr int PST = 68;  // P row stride: breaks the power-of-2 bank pattern (R3: conflicts -> 0)
    __shared__ __attribute__((aligned(16))) u16 Plds[2][16 * PST];
    u16* pl = Plds[w];
    u16* plw = pl + (lq * 4) * PST + lr;            // write base; (r,ct) offsets are immediates
    const u16* plr = pl + lr * PST + lq * 8;        // read base (A-fragment layout)

    short8 qf0 = *(const short8*)&Qp[(size_t)(i0 + lr) * 64 + lq * 8];
    short8 qf1 = *(const short8*)&Qp[(size_t)(i0 + lr) * 64 + 32 + lq * 8];

    f32x4 of[4];
#pragma unroll
    for (int nt = 0; nt < 4; ++nt) of[nt] = (f32x4){0.f, 0.f, 0.f, 0.f};
    float lsum[4] = {0.f, 0.f, 0.f, 0.f};
    const int rowi_base = i0 + lq * 4;

    const u16* kp = Kp + (size_t)lr * 64 + lq * 8;  // +ct*1024 within tile; +4096 per tile
    const u16* vp = Vp + (size_t)lr * NN + lq * 8;  // +nt*16*NN within tile; +64 per tile

    const int ntile = (i0 >> 6) + 1;
    for (int jt = 0; jt < ntile; ++jt) {
        const bool masked = (jt == ntile - 1);
        const int j0 = jt << 6;
        // ---- S = Q K^T for 16x64 ----
        f32x4 s[4];
#pragma unroll
        for (int ct = 0; ct < 4; ++ct) {
            short8 kf0 = *(const short8*)&kp[ct * 1024];
            short8 kf1 = *(const short8*)&kp[ct * 1024 + 32];
            f32x4 t = (f32x4){0.f, 0.f, 0.f, 0.f};
            t = mfma16(qf0, kf0, t);
            t = mfma16(qf1, kf1, t);
            s[ct] = t;
        }
        kp += 4096;
        // ---- prefetch V fragments (fly under the softmax VALU) ----
        short8 vf0[4], vf1[4];
#pragma unroll
        for (int nt = 0; nt < 4; ++nt) {
            vf0[nt] = *(const short8*)&vp[(size_t)nt * 16 * NN];
            vf1[nt] = *(const short8*)&vp[(size_t)nt * 16 * NN + 32];
        }
        vp += 64;
        // ---- softcap+softmax numerator, fixed max 6.25:
        //  p = exp(6.25*tanh(s/50) - 6.25) = exp(-12.5/(e+1)),  e = exp(0.04*s)
        //  exp2-folded: e = exp2(s*C1); p = exp2(-18.0336565/(e+1))
#pragma unroll
        for (int ct = 0; ct < 4; ++ct)
#pragma unroll
            for (int r = 0; r < 4; ++r) {
                float e = fastexp2(s[ct][r] * (0.04f * 1.44269504f));
                float p = fastexp2(-18.0336565f * fastrcp(e + 1.0f));
                if (masked) {
                    int col = j0 + ct * 16 + lr;
                    p = (col <= rowi_base + r) ? p : 0.0f;
                }
                lsum[r] += p;
                plw[r * PST + ct * 16] = f2b(p);
            }
        // C-layout -> LDS -> A-layout (wave-local; DS unit is in-order per wave; pin compiler)
        asm volatile("s_waitcnt lgkmcnt(0)" ::: "memory");
        short8 pf0 = *(const short8*)&plr[0];
        short8 pf1 = *(const short8*)&plr[32];
#pragma unroll
        for (int nt = 0; nt < 4; ++nt) {
            of[nt] = mfma16(pf0, vf0[nt], of[nt]);
            of[nt] = mfma16(pf1, vf1[nt], of[nt]);
        }
    }
    // one row-sum reduction at the end (lanes sharing a row differ only in lr bits)
#pragma unroll
    for (int r = 0; r < 4; ++r) {
        float s2 = lsum[r];
#pragma unroll
        for (int d = 1; d < 16; d <<= 1) s2 += __shfl_xor(s2, d);
        lsum[r] = fastrcp(s2);
    }
#pragma unroll
    for (int nt = 0; nt < 4; ++nt)
#pragma unroll
        for (int r = 0; r < 4; ++r)
            Op[(size_t)(rowi_base + r) * 64 + nt * 16 + lr] = f2b(of[nt][r] * lsum[r]);
}

// ---------------- sum g=2 group outputs: AO[b,n,h*64+d] = O[b,2h,n,d]+O[b,2h+1,n,d] ----------------
__global__ __launch_bounds__(256) void k_gsum(const u16* __restrict__ O, u16* __restrict__ AO) {
    int idx = blockIdx.x * 256 + threadIdx.x;  // B*N*512
    int c = idx & 511, row = idx >> 9;
    int b = row >> 11, n = row & 2047;
    int hh = c >> 6, d = c & 63;
    float a = b2f(O[((size_t)(b * QHH + 2 * hh) * NN + n) * 64 + d]);
    float bb = b2f(O[((size_t)(b * QHH + 2 * hh + 1) * NN + n) * 64 + d]);
    AO[(size_t)row * 512 + c] = f2b(a + bb);
}

extern "C" void kernel_launch(void* const* d_in, const int* in_sizes, int n_in,
                              void* d_out, int out_size, void* d_ws, size_t ws_size,
                              hipStream_t stream) {
    const float* tokens = (const float*)d_in[0];
    const float* norm_w = (const float*)d_in[1];
    const float* Wq = (const float*)d_in[2];
    const float* Wkv = (const float*)d_in[3];
    const float* Wout = (const float*)d_in[4];
    const float* q_gamma = (const float*)d_in[5];
    const float* k_gamma = (const float*)d_in[6];
    float* out = (float*)d_out;

    char* ws = (char*)d_ws;
    u16* xb = (u16*)(ws + 0);             // 8,388,608 B  [4096,1024]
    u16* WqT = (u16*)(ws + 8388608);      // 2,097,152 B
    u16* WkvT = (u16*)(ws + 10485760);    // 2,097,152 B
    u16* WoutT = (u16*)(ws + 12582912);   // 1,048,576 B
    u16* q_raw = (u16*)(ws + 13631488);   // 8,388,608 B
    u16* kv_raw = (u16*)(ws + 22020096);  // 8,388,608 B
    u16* kn = (u16*)(ws + 30408704);      // 4,194,304 B
    u16* vtb = (u16*)(ws + 34603008);     // 4,194,304 B
    // total 38,797,312 B; lifetime-based aliases (stream-ordered, no overlap in use):
    u16* qn = xb;       // xb dead after the two QKV GEMMs
    u16* Obuf = q_raw;  // q_raw dead after k_headnorm
    u16* AO = kv_raw;   // kv_raw dead after k_headnorm

    k_rmsnorm<<<4096, 256, 0, stream>>>(tokens, norm_w, xb);
    k_transpose<<<dim3(32, 32), 256, 0, stream>>>(Wq, WqT, 1024, 1024);
    k_transpose<<<dim3(32, 32), 256, 0, stream>>>(Wkv, WkvT, 1024, 1024);
    k_transpose<<<dim3(32, 16), 256, 0, stream>>>(Wout, WoutT, 512, 1024);
    k_gemm_bt<u16><<<dim3(8, 32), 256, 0, stream>>>(xb, WqT, q_raw, 4096, 1024, 1024);
    k_gemm_bt<u16><<<dim3(8, 32), 256, 0, stream>>>(xb, WkvT, kv_raw, 4096, 1024, 1024);
    k_headnorm<<<4096, 256, 0, stream>>>(q_raw, kv_raw, q_gamma, k_gamma, qn, kn, vtb);
    k_attn<<<dim3(32, 64), 128, 0, stream>>>(qn, kn, vtb, Obuf);
    k_gsum<<<8192, 256, 0, stream>>>(Obuf, AO);
    k_gemm_bt<float><<<dim3(8, 32), 256, 0, stream>>>(AO, WoutT, out, 4096, 1024, 512);
}